// Round 1
// baseline (550.780 us; speedup 1.0000x reference)
//
#include <hip/hip_runtime.h>
#include <stdint.h>

#define NB 8192
#define ND 2048
#define NE 8
#define NG 4
#define NP 512
#define NH 192

typedef unsigned short u16;
typedef _Float16 half_t;
typedef half_t f16x8 __attribute__((ext_vector_type(8)));
typedef float f32x4 __attribute__((ext_vector_type(4)));

__device__ __forceinline__ void gload16(const void* g, void* l) {
  __builtin_amdgcn_global_load_lds(
      (const __attribute__((address_space(1))) void*)g,
      (__attribute__((address_space(3))) void*)l, 16, 0, 0);
}

// ---------------- routing + x -> fp16 conversion ----------------
__global__ __launch_bounds__(256) void k_route(
    const float* __restrict__ x,
    const float* __restrict__ Wg, const float* __restrict__ bg,
    const float* __restrict__ Wp, const float* __restrict__ bp,
    const float* __restrict__ Wgg, const float* __restrict__ bgg,
    half_t* __restrict__ xh,
    int* __restrict__ rowl, float* __restrict__ wl, int* __restrict__ cnt)
{
  const int b = blockIdx.x;
  const int t = threadIdx.x;
  __shared__ double red[256];

  const float* xr = x + (size_t)b * ND;
  const float4 v0 = ((const float4*)xr)[t * 2];
  const float4 v1 = ((const float4*)xr)[t * 2 + 1];
  float f[8] = {v0.x, v0.y, v0.z, v0.w, v1.x, v1.y, v1.z, v1.w};
  double s = 0.0;
  __align__(16) half_t hb[8];
#pragma unroll
  for (int i = 0; i < 8; i++) { s += (double)f[i]; hb[i] = (half_t)f[i]; }
  *reinterpret_cast<int4*>(xh + (size_t)b * ND + t * 8) = *reinterpret_cast<const int4*>(hb);

  red[t] = s;
  __syncthreads();
  for (int off = 128; off > 0; off >>= 1) {
    if (t < off) red[t] += red[t + off];
    __syncthreads();
  }
  const double qm = red[0] / (double)ND;
  __syncthreads();

  double part = 0.0;
  if (t < NH) {
    double ang = qm * (7.0 * (double)(t + 1));
    part = cos(ang) + sin(ang);
  }
  red[t] = part;
  __syncthreads();
  for (int off = 128; off > 0; off >>= 1) {
    if (t < off) red[t] += red[t + off];
    __syncthreads();
  }

  if (t == 0) {
    const double tm = red[0] / (2.0 * (double)NH);
    const double gi0 = tm, gi1 = 32.0 / 2048.0;  // mean spike rate is constant
    double lg[NE];
    for (int e = 0; e < NE; e++) {
      int g = e & 3;
      double l = gi0 * (double)Wg[e] + gi1 * (double)Wg[NE + e] + (double)bg[e];
      l -= 0.1 * (gi0 * (double)Wp[e] + gi1 * (double)Wp[NE + e] + (double)bp[e]);
      l += gi0 * (double)Wgg[g] + gi1 * (double)Wgg[NG + g] + (double)bgg[g];
      lg[e] = l;
    }
    int e0 = 0;
    for (int e = 1; e < NE; e++) if (lg[e] > lg[e0]) e0 = e;
    int e1 = (e0 == 0) ? 1 : 0;
    for (int e = 0; e < NE; e++) if (e != e0 && lg[e] > lg[e1]) e1 = e;
    const double mx = lg[e0];
    double ps = 0.0;
    for (int e = 0; e < NE; e++) ps += exp(lg[e] - mx);
    const double p0 = exp(lg[e0] - mx) / ps;
    const double p1 = exp(lg[e1] - mx) / ps;
    const double den = p0 + p1 + 1e-9;
    const float w0 = (float)(p0 / den), w1 = (float)(p1 / den);
    int pos0 = atomicAdd(&cnt[e0], 1);
    rowl[e0 * NB + pos0] = b;
    wl[e0 * NB + pos0] = w0;
    int pos1 = atomicAdd(&cnt[8 + e1], 1);
    rowl[(8 + e1) * NB + pos1] = b;
    wl[(8 + e1) * NB + pos1] = w1;
  }
}

// ---------------- weight transpose + fp16 convert ----------------
// which=0: W1 [E][2048][512] -> w1t [E][512][2048]
// which=1: W2 [E][512][2048] -> w2t [E][2048][512]
__global__ __launch_bounds__(256) void k_cvt_w(
    const float* __restrict__ W1, const float* __restrict__ W2,
    half_t* __restrict__ w1t, half_t* __restrict__ w2t)
{
  const int which = blockIdx.y;
  const int R = which ? NP : ND;
  const int C = which ? ND : NP;
  const float* src = which ? W2 : W1;
  half_t* dst = which ? w2t : w1t;
  const int tiles_c = C >> 5;
  const int tiles_per_e = (R >> 5) * tiles_c;
  int id = blockIdx.x;
  int e = id / tiles_per_e;
  int rem = id - e * tiles_per_e;
  int tr = rem / tiles_c, tc = rem - tr * tiles_c;
  __shared__ float tile[32][33];
  const int tx = threadIdx.x & 31, ty = threadIdx.x >> 5;
  const float* s = src + (size_t)e * R * C + (size_t)(tr * 32) * C + tc * 32;
#pragma unroll
  for (int i = 0; i < 4; i++)
    tile[ty + i * 8][tx] = s[(size_t)(ty + i * 8) * C + tx];
  __syncthreads();
  half_t* d = dst + (size_t)e * R * C + (size_t)(tc * 32) * R + tr * 32;
#pragma unroll
  for (int i = 0; i < 4; i++)
    d[(size_t)(ty + i * 8) * R + tx] = (half_t)tile[tx][ty + i * 8];
}

__global__ void k_prefix(const int* __restrict__ cnt, int* __restrict__ pbase) {
  if (threadIdx.x == 0 && blockIdx.x == 0) {
    int s = 0;
    for (int i = 0; i < 16; i++) { pbase[i] = s; s += cnt[i]; }
  }
}

// ---------------- GEMM1: H = relu(gather(x) @ W1[e] + b1[e]) ----------------
__global__ __launch_bounds__(256) void k_gemm1(
    const half_t* __restrict__ xh, const half_t* __restrict__ w1t,
    const float* __restrict__ b1,
    const int* __restrict__ rowl, const int* __restrict__ cnt,
    const int* __restrict__ pbase, half_t* __restrict__ Hbuf)
{
  const int bucket = blockIdx.z;
  const int count = cnt[bucket];
  const int m0 = blockIdx.y * 128;
  if (m0 >= count) return;
  const int e = bucket & 7;
  const int n0 = blockIdx.x * 128;
  const int t = threadIdx.x;

  __shared__ __align__(16) half_t As[128 * 32];
  __shared__ __align__(16) half_t Bs[128 * 32];
  __shared__ int rows_s[128];

  if (t < 128) {
    int mi = m0 + t;
    rows_s[t] = rowl[bucket * NB + (mi < count ? mi : m0)];
  }
  __syncthreads();

  const int w = t >> 6, lane = t & 63;
  const int c0 = w * 128 + lane, c1 = c0 + 64;
  const half_t* gA0 = xh + (size_t)rows_s[c0 >> 2] * ND + (c0 & 3) * 8;
  const half_t* gA1 = xh + (size_t)rows_s[c1 >> 2] * ND + (c1 & 3) * 8;
  const half_t* w1te = w1t + (size_t)e * NP * ND;
  const half_t* gB0 = w1te + (size_t)(n0 + (c0 >> 2)) * ND + (c0 & 3) * 8;
  const half_t* gB1 = w1te + (size_t)(n0 + (c1 >> 2)) * ND + (c1 & 3) * 8;
  half_t* lA0 = As + (w * 128) * 8;
  half_t* lA1 = As + (w * 128 + 64) * 8;
  half_t* lB0 = Bs + (w * 128) * 8;
  half_t* lB1 = Bs + (w * 128 + 64) * 8;

  const int wr = w >> 1, wc = w & 1;
  const int lrow = lane & 15, lk = lane >> 4;

  f32x4 acc[4][4];
#pragma unroll
  for (int i = 0; i < 4; i++)
#pragma unroll
    for (int j = 0; j < 4; j++) {
      acc[i][j][0] = 0.f; acc[i][j][1] = 0.f; acc[i][j][2] = 0.f; acc[i][j][3] = 0.f;
    }

  for (int k0 = 0; k0 < ND; k0 += 32) {
    gload16(gA0 + k0, lA0);
    gload16(gA1 + k0, lA1);
    gload16(gB0 + k0, lB0);
    gload16(gB1 + k0, lB1);
    __syncthreads();
    f16x8 af[4], bf[4];
#pragma unroll
    for (int i = 0; i < 4; i++) {
      af[i] = *reinterpret_cast<const f16x8*>(&As[(wr * 64 + i * 16 + lrow) * 32 + lk * 8]);
      bf[i] = *reinterpret_cast<const f16x8*>(&Bs[(wc * 64 + i * 16 + lrow) * 32 + lk * 8]);
    }
#pragma unroll
    for (int mi = 0; mi < 4; mi++)
#pragma unroll
      for (int ni = 0; ni < 4; ni++)
        acc[mi][ni] = __builtin_amdgcn_mfma_f32_16x16x32_f16(af[mi], bf[ni], acc[mi][ni], 0, 0, 0);
    __syncthreads();
  }

  const int pb = pbase[bucket];
#pragma unroll
  for (int mi = 0; mi < 4; mi++) {
#pragma unroll
    for (int i = 0; i < 4; i++) {
      int lm = wr * 64 + mi * 16 + lk * 4 + i;
      if (m0 + lm < count) {
        size_t prow = (size_t)(pb + m0 + lm) * NP;
#pragma unroll
        for (int ni = 0; ni < 4; ni++) {
          int col = n0 + wc * 64 + ni * 16 + lrow;
          float v = acc[mi][ni][i] + b1[e * NP + col];
          Hbuf[prow + col] = (half_t)(v > 0.f ? v : 0.f);
        }
      }
    }
  }
}

// ---------------- GEMM2: out[r] (=|+=) w * (H @ W2[e] + b2[e]) ----------------
__global__ __launch_bounds__(256) void k_gemm2(
    const half_t* __restrict__ Hbuf, const half_t* __restrict__ w2t,
    const float* __restrict__ b2,
    const int* __restrict__ rowl, const float* __restrict__ wl,
    const int* __restrict__ cnt, const int* __restrict__ pbase,
    float* __restrict__ out, int bucket0, int addmode)
{
  const int bucket = bucket0 + blockIdx.z;
  const int count = cnt[bucket];
  const int m0 = blockIdx.y * 128;
  if (m0 >= count) return;
  const int e = bucket & 7;
  const int n0 = blockIdx.x * 128;
  const int t = threadIdx.x;

  __shared__ __align__(16) half_t As[128 * 32];
  __shared__ __align__(16) half_t Bs[128 * 32];
  __shared__ int rows_s[128];
  __shared__ float ws_s[128];

  if (t < 128) {
    int mi = m0 + t;
    int idx = bucket * NB + (mi < count ? mi : m0);
    rows_s[t] = rowl[idx];
    ws_s[t] = wl[idx];
  }
  __syncthreads();

  const int w = t >> 6, lane = t & 63;
  const int c0 = w * 128 + lane, c1 = c0 + 64;
  const int pb = pbase[bucket];
  const half_t* gA0 = Hbuf + (size_t)(pb + m0 + (c0 >> 2)) * NP + (c0 & 3) * 8;
  const half_t* gA1 = Hbuf + (size_t)(pb + m0 + (c1 >> 2)) * NP + (c1 & 3) * 8;
  const half_t* w2te = w2t + (size_t)e * ND * NP;
  const half_t* gB0 = w2te + (size_t)(n0 + (c0 >> 2)) * NP + (c0 & 3) * 8;
  const half_t* gB1 = w2te + (size_t)(n0 + (c1 >> 2)) * NP + (c1 & 3) * 8;
  half_t* lA0 = As + (w * 128) * 8;
  half_t* lA1 = As + (w * 128 + 64) * 8;
  half_t* lB0 = Bs + (w * 128) * 8;
  half_t* lB1 = Bs + (w * 128 + 64) * 8;

  const int wr = w >> 1, wc = w & 1;
  const int lrow = lane & 15, lk = lane >> 4;

  f32x4 acc[4][4];
#pragma unroll
  for (int i = 0; i < 4; i++)
#pragma unroll
    for (int j = 0; j < 4; j++) {
      acc[i][j][0] = 0.f; acc[i][j][1] = 0.f; acc[i][j][2] = 0.f; acc[i][j][3] = 0.f;
    }

  for (int k0 = 0; k0 < NP; k0 += 32) {
    gload16(gA0 + k0, lA0);
    gload16(gA1 + k0, lA1);
    gload16(gB0 + k0, lB0);
    gload16(gB1 + k0, lB1);
    __syncthreads();
    f16x8 af[4], bf[4];
#pragma unroll
    for (int i = 0; i < 4; i++) {
      af[i] = *reinterpret_cast<const f16x8*>(&As[(wr * 64 + i * 16 + lrow) * 32 + lk * 8]);
      bf[i] = *reinterpret_cast<const f16x8*>(&Bs[(wc * 64 + i * 16 + lrow) * 32 + lk * 8]);
    }
#pragma unroll
    for (int mi = 0; mi < 4; mi++)
#pragma unroll
      for (int ni = 0; ni < 4; ni++)
        acc[mi][ni] = __builtin_amdgcn_mfma_f32_16x16x32_f16(af[mi], bf[ni], acc[mi][ni], 0, 0, 0);
    __syncthreads();
  }

#pragma unroll
  for (int mi = 0; mi < 4; mi++) {
#pragma unroll
    for (int i = 0; i < 4; i++) {
      int lm = wr * 64 + mi * 16 + lk * 4 + i;
      if (m0 + lm < count) {
        int r = rows_s[lm];
        float wgt = ws_s[lm];
        float* orow = out + (size_t)r * ND;
#pragma unroll
        for (int ni = 0; ni < 4; ni++) {
          int col = n0 + wc * 64 + ni * 16 + lrow;
          float v = (acc[mi][ni][i] + b2[e * ND + col]) * wgt;
          if (addmode) orow[col] += v;
          else orow[col] = v;
        }
      }
    }
  }
}

extern "C" void kernel_launch(void* const* d_in, const int* in_sizes, int n_in,
                              void* d_out, int out_size, void* d_ws, size_t ws_size,
                              hipStream_t stream)
{
  const float* x   = (const float*)d_in[0];
  const float* Wg  = (const float*)d_in[1];
  const float* bg  = (const float*)d_in[2];
  const float* Wp  = (const float*)d_in[3];
  const float* bp  = (const float*)d_in[4];
  const float* Wgg = (const float*)d_in[5];
  const float* bgg = (const float*)d_in[6];
  const float* W1  = (const float*)d_in[7];
  const float* b1  = (const float*)d_in[8];
  const float* W2  = (const float*)d_in[9];
  const float* b2  = (const float*)d_in[10];
  float* out = (float*)d_out;

  char* ws = (char*)d_ws;
  const size_t OFF_XH  = 0;
  const size_t OFF_W1T = OFF_XH  + (size_t)NB * ND * 2;           // 32 MB
  const size_t OFF_W2T = OFF_W1T + (size_t)NE * NP * ND * 2;      // +16 MB
  const size_t OFF_H   = OFF_W2T + (size_t)NE * ND * NP * 2;      // +16 MB
  const size_t OFF_ROWL= OFF_H   + (size_t)(2 * NB + 128) * NP * 2; // +~16 MB (padded)
  const size_t OFF_WL  = OFF_ROWL + (size_t)16 * NB * 4;
  const size_t OFF_CNT = OFF_WL  + (size_t)16 * NB * 4;
  const size_t OFF_PB  = OFF_CNT + 64;

  half_t* xh   = (half_t*)(ws + OFF_XH);
  half_t* w1t  = (half_t*)(ws + OFF_W1T);
  half_t* w2t  = (half_t*)(ws + OFF_W2T);
  half_t* Hbuf = (half_t*)(ws + OFF_H);
  int*    rowl = (int*)(ws + OFF_ROWL);
  float*  wl   = (float*)(ws + OFF_WL);
  int*    cnt  = (int*)(ws + OFF_CNT);
  int*    pb   = (int*)(ws + OFF_PB);

  hipMemsetAsync(cnt, 0, 64, stream);
  k_route<<<NB, 256, 0, stream>>>(x, Wg, bg, Wp, bp, Wgg, bgg, xh, rowl, wl, cnt);
  k_cvt_w<<<dim3(8192, 2, 1), 256, 0, stream>>>(W1, W2, w1t, w2t);
  k_prefix<<<1, 64, 0, stream>>>(cnt, pb);
  k_gemm1<<<dim3(4, 64, 16), 256, 0, stream>>>(xh, w1t, b1, rowl, cnt, pb, Hbuf);
  k_gemm2<<<dim3(16, 64, 8), 256, 0, stream>>>(Hbuf, w2t, b2, rowl, wl, cnt, pb, out, 0, 0);
  k_gemm2<<<dim3(16, 64, 8), 256, 0, stream>>>(Hbuf, w2t, b2, rowl, wl, cnt, pb, out, 8, 1);
}